// Round 1
// baseline (12342.410 us; speedup 1.0000x reference)
//
#include <hip/hip_runtime.h>
#include <hip/hip_bf16.h>

// Sizes (fixed by the problem)
#define TT 256
#define BB 128
#define EE 256
#define HH 512
#define KK 7
#define NWG_DIR 256   // wgs per direction in the persistent kernel

// ---------------------------------------------------------------------------
// K1: embedding gather + transpose:  xsT[t][e][b] = embed[ids[t][b]][e]
// ---------------------------------------------------------------------------
__global__ __launch_bounds__(256) void embed_transpose_kernel(
    const int* __restrict__ ids, const float* __restrict__ emb,
    float* __restrict__ xsT) {
  const int t = blockIdx.x;
  const int tid = threadIdx.x;
  __shared__ float buf[128][65];
  __shared__ int sid[128];
  if (tid < 128) sid[tid] = ids[t * BB + tid];
  __syncthreads();
  for (int es = 0; es < EE; es += 64) {
    // load phase: thread -> (row b = tid/2, half = tid%2), 32 consecutive floats
    const int b = tid >> 1, hf = tid & 1;
    const float* src = emb + (size_t)sid[b] * EE + es + hf * 32;
#pragma unroll
    for (int j = 0; j < 32; ++j) buf[b][hf * 32 + j] = src[j];
    __syncthreads();
    // store phase: coalesced over b
    const int bb = tid & 127, eh = tid >> 7;
#pragma unroll
    for (int p = 0; p < 32; ++p) {
      const int el = p * 2 + eh;
      xsT[((size_t)t * EE + es + el) * BB + bb] = buf[bb][el];
    }
    __syncthreads();
  }
}

// ---------------------------------------------------------------------------
// Per-direction grid barrier (monotonic count, release/acquire at agent scope)
// ---------------------------------------------------------------------------
__device__ __forceinline__ void grid_barrier(int* cnt, int* gen, int target) {
  __syncthreads();
  if (threadIdx.x == 0) {
    __threadfence();  // make this wg's global writes visible device-wide
    const int old = __hip_atomic_fetch_add(cnt, 1, __ATOMIC_ACQ_REL,
                                           __HIP_MEMORY_SCOPE_AGENT);
    if (old == NWG_DIR * target - 1) {
      __hip_atomic_store(gen, target, __ATOMIC_RELEASE, __HIP_MEMORY_SCOPE_AGENT);
    } else {
      while (__hip_atomic_load(gen, __ATOMIC_RELAXED, __HIP_MEMORY_SCOPE_AGENT) <
             target) {
        __builtin_amdgcn_s_sleep(2);
      }
      __builtin_amdgcn_fence(__ATOMIC_ACQUIRE, "agent");
    }
  }
  __syncthreads();
}

// ---------------------------------------------------------------------------
// K2: persistent BiLSTM. 512 wgs x 256 thr.  wg = (dir, 2 h-columns).
//   waves: (row-half r = wv&1, k-split ks = wv>>1).  8 gate-cols per wave.
//   Wl rows: [i0,i1,f0,f1,g0,g1,o0,o1]  (gate g row = g*512 + j0 + (r&1))
// ---------------------------------------------------------------------------
__global__ __launch_bounds__(256, 2) void bilstm_kernel(
    const float* __restrict__ xsT,
    const float* __restrict__ Wih_f, const float* __restrict__ Whh_f,
    const float* __restrict__ bih_f, const float* __restrict__ bhh_f,
    const float* __restrict__ Wih_b, const float* __restrict__ Whh_b,
    const float* __restrict__ bih_b, const float* __restrict__ bhh_b,
    float* __restrict__ hT, __hip_bfloat16* __restrict__ hs,
    int* __restrict__ bar) {
  const int wg = blockIdx.x;
  const int dir = wg >> 8;
  const int j0 = (wg & 255) * 2;
  const int tid = threadIdx.x;
  const float* Wih = dir ? Wih_b : Wih_f;
  const float* Whh = dir ? Whh_b : Whh_f;
  const float* bih = dir ? bih_b : bih_f;
  const float* bhh = dir ? bhh_b : bhh_f;
  int* cnt = bar + (dir ? 64 : 0);
  int* gen = bar + (dir ? 96 : 32);

  __shared__ __align__(16) float Wl[8][EE + HH];  // 24 KB
  __shared__ float bl[8];
  __shared__ float gt[2][128][9];  // partial gate tiles (per k-split)
  __shared__ float cl[2][128];     // cell state

  // stage weights into LDS (once; persists across all steps)
  for (int idx = tid; idx < 8 * (EE + HH); idx += 256) {
    const int r = idx / (EE + HH);
    const int k = idx - r * (EE + HH);
    const int grow = (r >> 1) * HH + j0 + (r & 1);
    Wl[r][k] = (k < EE) ? Wih[grow * EE + k] : Whh[grow * HH + (k - EE)];
  }
  if (tid < 8) {
    const int grow = (tid >> 1) * HH + j0 + (tid & 1);
    bl[tid] = bih[grow] + bhh[grow];
  }
  {
    const int b2 = tid & 127, jj = tid >> 7;
    hT[((size_t)dir * HH + j0 + jj) * BB + b2] = 0.f;
    cl[jj][b2] = 0.f;
  }
  int tgt = 1;
  grid_barrier(cnt, gen, tgt);
  ++tgt;

  const int wv = tid >> 6, lane = tid & 63;
  const int row0 = (wv & 1) * 64;
  const int ks = wv >> 1;
  const int b = row0 + lane;
  const float* hb = hT + (size_t)dir * HH * BB + b;

  for (int s = 0; s < TT; ++s) {
    const int t = dir ? (TT - 1 - s) : s;
    float a[8] = {0.f, 0.f, 0.f, 0.f, 0.f, 0.f, 0.f, 0.f};
    if (ks == 0) {
      const float* xc = xsT + (size_t)t * (EE * BB) + b;
#pragma unroll 2
      for (int k = 0; k < 256; k += 4) {
        const float x0 = xc[k * 128], x1 = xc[k * 128 + 128];
        const float x2 = xc[k * 128 + 256], x3 = xc[k * 128 + 384];
#pragma unroll
        for (int c = 0; c < 8; ++c) {
          const float4 w = *(const float4*)&Wl[c][k];
          a[c] = fmaf(x0, w.x, fmaf(x1, w.y, fmaf(x2, w.z, fmaf(x3, w.w, a[c]))));
        }
      }
#pragma unroll 2
      for (int k = 0; k < 128; k += 4) {
        const float h0 = hb[k * 128], h1 = hb[k * 128 + 128];
        const float h2 = hb[k * 128 + 256], h3 = hb[k * 128 + 384];
#pragma unroll
        for (int c = 0; c < 8; ++c) {
          const float4 w = *(const float4*)&Wl[c][EE + k];
          a[c] = fmaf(h0, w.x, fmaf(h1, w.y, fmaf(h2, w.z, fmaf(h3, w.w, a[c]))));
        }
      }
    } else {
#pragma unroll 2
      for (int k = 128; k < 512; k += 4) {
        const float h0 = hb[k * 128], h1 = hb[k * 128 + 128];
        const float h2 = hb[k * 128 + 256], h3 = hb[k * 128 + 384];
#pragma unroll
        for (int c = 0; c < 8; ++c) {
          const float4 w = *(const float4*)&Wl[c][EE + k];
          a[c] = fmaf(h0, w.x, fmaf(h1, w.y, fmaf(h2, w.z, fmaf(h3, w.w, a[c]))));
        }
      }
    }
#pragma unroll
    for (int c = 0; c < 8; ++c) gt[ks][b][c] = a[c];
    __syncthreads();
    // cell update: thread -> (b2, jj)
    {
      const int b2 = tid & 127, jj = tid >> 7;
      const float i_ = gt[0][b2][0 + jj] + gt[1][b2][0 + jj] + bl[0 + jj];
      const float f_ = gt[0][b2][2 + jj] + gt[1][b2][2 + jj] + bl[2 + jj];
      const float g_ = gt[0][b2][4 + jj] + gt[1][b2][4 + jj] + bl[4 + jj];
      const float o_ = gt[0][b2][6 + jj] + gt[1][b2][6 + jj] + bl[6 + jj];
      const float cp = cl[jj][b2];
      const float si = 1.f / (1.f + __expf(-i_));
      const float sf = 1.f / (1.f + __expf(-f_));
      const float so = 1.f / (1.f + __expf(-o_));
      const float gcl = fminf(fmaxf(g_, -30.f), 30.f);
      const float eg = __expf(-2.f * gcl);
      const float tg = (1.f - eg) / (1.f + eg);
      const float cn = fmaf(sf, cp, si * tg);
      const float ccl = fminf(fmaxf(cn, -30.f), 30.f);
      const float ec = __expf(-2.f * ccl);
      const float tc = (1.f - ec) / (1.f + ec);
      const float hn = so * tc;
      cl[jj][b2] = cn;
      hT[((size_t)dir * HH + j0 + jj) * BB + b2] = hn;
      hs[(((size_t)dir * TT + t) * HH + j0 + jj) * BB + b2] = __float2bfloat16(hn);
    }
    grid_barrier(cnt, gen, tgt);
    ++tgt;
  }
}

// ---------------------------------------------------------------------------
// K3: emissions  em[b][t][k] = hs_f[t][:,b].linW[k][:512] + hs_b.linW[k][512:] + lb
// ---------------------------------------------------------------------------
__global__ __launch_bounds__(128) void emissions_kernel(
    const __hip_bfloat16* __restrict__ hs, const float* __restrict__ linW,
    const float* __restrict__ linb, float* __restrict__ em) {
  const int t = blockIdx.x, tid = threadIdx.x;  // tid = b
  __shared__ float W[KK][2 * HH];
  __shared__ float lb[KK];
  for (int i = tid; i < KK * 2 * HH; i += 128) W[i / (2 * HH)][i % (2 * HH)] = linW[i];
  if (tid < KK) lb[tid] = linb[tid];
  __syncthreads();
  float acc[KK];
#pragma unroll
  for (int k = 0; k < KK; ++k) acc[k] = lb[k];
  const __hip_bfloat16* hf = hs + ((size_t)t * HH) * BB + tid;
  const __hip_bfloat16* hbp = hs + ((size_t)(TT + t) * HH) * BB + tid;
  for (int j = 0; j < HH; ++j) {
    const float xf = __bfloat162float(hf[j * BB]);
    const float xb = __bfloat162float(hbp[j * BB]);
#pragma unroll
    for (int k = 0; k < KK; ++k)
      acc[k] = fmaf(xf, W[k][j], fmaf(xb, W[k][HH + j], acc[k]));
  }
  float* o = em + ((size_t)tid * TT + t) * KK;
#pragma unroll
  for (int k = 0; k < KK; ++k) o[k] = acc[k];
}

// ---------------------------------------------------------------------------
// K4: CRF forward algorithm + gold score.  One wave per sequence, lanes 0..6.
// ---------------------------------------------------------------------------
__global__ __launch_bounds__(64) void crf_kernel(
    const float* __restrict__ em, const int* __restrict__ lab,
    const float* __restrict__ trans, const float* __restrict__ st_,
    const float* __restrict__ en_, float* __restrict__ partial) {
  const int b = blockIdx.x;
  const int lane = threadIdx.x;
  __shared__ float tr[49], st[7], en[7], al[2][7];
  if (lane < 49) tr[lane] = trans[lane];
  if (lane < 7) {
    st[lane] = st_[lane];
    en[lane] = en_[lane];
  }
  const float* e = em + (size_t)b * TT * KK;
  const int* lb = lab + (size_t)b * TT;
  if (lane < 7) al[0][lane] = st_[lane] + e[lane];
  __syncthreads();
  float gold = 0.f;
  int lp = lb[0];
  if (lane == 0) gold = st[lp] + e[lp];
  int p = 0;
  for (int t = 1; t < TT; ++t) {
    const float* et = e + t * KK;
    if (lane < 7) {
      float v[7], m = -1e30f;
#pragma unroll
      for (int k = 0; k < 7; ++k) {
        v[k] = al[p][k] + tr[k * 7 + lane];
        m = fmaxf(m, v[k]);
      }
      float ssum = 0.f;
#pragma unroll
      for (int k = 0; k < 7; ++k) ssum += __expf(v[k] - m);
      al[p ^ 1][lane] = m + __logf(ssum) + et[lane];
    }
    if (lane == 0) {
      const int lt = lb[t];
      gold += tr[lp * 7 + lt] + et[lt];
      lp = lt;
    }
    __syncthreads();
    p ^= 1;
  }
  if (lane == 0) {
    float m = -1e30f, v[7];
#pragma unroll
    for (int k = 0; k < 7; ++k) {
      v[k] = al[p][k] + en[k];
      m = fmaxf(m, v[k]);
    }
    float ssum = 0.f;
#pragma unroll
    for (int k = 0; k < 7; ++k) ssum += __expf(v[k] - m);
    partial[b] = (m + __logf(ssum)) - gold;
  }
}

// K5: final reduce of 128 per-sequence partials -> scalar NLL
__global__ __launch_bounds__(128) void reduce_kernel(const float* __restrict__ partial,
                                                     float* __restrict__ out) {
  __shared__ float r[128];
  const int tid = threadIdx.x;
  r[tid] = partial[tid];
  __syncthreads();
  for (int off = 64; off > 0; off >>= 1) {
    if (tid < off) r[tid] += r[tid + off];
    __syncthreads();
  }
  if (tid == 0) out[0] = r[0];
}

// ---------------------------------------------------------------------------
extern "C" void kernel_launch(void* const* d_in, const int* in_sizes, int n_in,
                              void* d_out, int out_size, void* d_ws, size_t ws_size,
                              hipStream_t stream) {
  const int* ids = (const int*)d_in[0];
  const int* lab = (const int*)d_in[1];
  const float* emb = (const float*)d_in[2];
  const float* Wih_f = (const float*)d_in[3];
  const float* Whh_f = (const float*)d_in[4];
  const float* bih_f = (const float*)d_in[5];
  const float* bhh_f = (const float*)d_in[6];
  const float* Wih_b = (const float*)d_in[7];
  const float* Whh_b = (const float*)d_in[8];
  const float* bih_b = (const float*)d_in[9];
  const float* bhh_b = (const float*)d_in[10];
  const float* linW = (const float*)d_in[11];
  const float* linb = (const float*)d_in[12];
  const float* trans = (const float*)d_in[13];
  const float* st = (const float*)d_in[14];
  const float* en = (const float*)d_in[15];
  float* out = (float*)d_out;

  // workspace layout (all 256B-aligned): ~102 MB total
  char* ws = (char*)d_ws;
  int* bar = (int*)ws;                                   // 512 B
  float* xsT = (float*)(ws + 512);                       // T*E*B f32 = 33.5 MB
  float* hT = xsT + (size_t)TT * EE * BB;                // 2*H*B f32 = 0.5 MB
  __hip_bfloat16* hs = (__hip_bfloat16*)(hT + (size_t)2 * HH * BB);  // 67 MB
  float* em = (float*)((char*)hs + (size_t)2 * TT * HH * BB * sizeof(__hip_bfloat16));
  float* partial = em + (size_t)BB * TT * KK;

  hipMemsetAsync(bar, 0, 512, stream);  // barrier counters must start at 0

  embed_transpose_kernel<<<dim3(TT), dim3(256), 0, stream>>>(ids, emb, xsT);

  void* args[] = {(void*)&xsT,   (void*)&Wih_f, (void*)&Whh_f, (void*)&bih_f,
                  (void*)&bhh_f, (void*)&Wih_b, (void*)&Whh_b, (void*)&bih_b,
                  (void*)&bhh_b, (void*)&hT,    (void*)&hs,    (void*)&bar};
  hipLaunchCooperativeKernel((void*)bilstm_kernel, dim3(2 * NWG_DIR), dim3(256),
                             args, 0, stream);

  emissions_kernel<<<dim3(TT), dim3(128), 0, stream>>>(hs, linW, linb, em);
  crf_kernel<<<dim3(BB), dim3(64), 0, stream>>>(em, lab, trans, st, en, partial);
  reduce_kernel<<<dim3(1), dim3(128), 0, stream>>>(partial, out);
}

// Round 2
// 3931.686 us; speedup vs baseline: 3.1392x; 3.1392x over previous
//
#include <hip/hip_runtime.h>
#include <hip/hip_bf16.h>

// Sizes (fixed by the problem)
#define TT 256
#define BB 128
#define EE 256
#define HH 512
#define KK 7
#define NWGD 64    // workgroups per direction in the persistent kernel
#define WLD 776    // padded LDS row for W tile: 768 + 8 bf16 (breaks bank conflicts)

typedef short bf16x8 __attribute__((ext_vector_type(8)));
typedef float f32x4 __attribute__((ext_vector_type(4)));
typedef unsigned short u16x8 __attribute__((ext_vector_type(8)));

__device__ __forceinline__ unsigned short f2bf(float x) {
  unsigned u = __builtin_bit_cast(unsigned, x);
  u += 0x7FFFu + ((u >> 16) & 1u);  // RNE
  return (unsigned short)(u >> 16);
}
__device__ __forceinline__ float bf2f(unsigned short b) {
  return __builtin_bit_cast(float, (unsigned)b << 16);
}

// ---------------------------------------------------------------------------
// K1: embedding gather -> bf16, layout xsb[t][b][e] (rows contiguous in e)
// ---------------------------------------------------------------------------
__global__ __launch_bounds__(256) void embed_kernel(
    const int* __restrict__ ids, const float* __restrict__ emb,
    unsigned short* __restrict__ xsb) {
  const int t = blockIdx.x, tid = threadIdx.x;
  const int b = tid >> 1, half = tid & 1;
  const int id = ids[t * BB + b];
  const float4* src = (const float4*)(emb + (size_t)id * EE + half * 128);
  unsigned short* dst = xsb + ((size_t)t * BB + b) * EE + half * 128;
#pragma unroll
  for (int i = 0; i < 32; ++i) {
    const float4 v = src[i];
    ushort4 o;
    o.x = f2bf(v.x); o.y = f2bf(v.y); o.z = f2bf(v.z); o.w = f2bf(v.w);
    *(ushort4*)(dst + i * 4) = o;
  }
}

// ---------------------------------------------------------------------------
// Per-direction grid barrier (monotonic count; proven in round-1 for
// cross-XCD visibility: threadfence release + agent-scope atomics + acquire)
// ---------------------------------------------------------------------------
__device__ __forceinline__ void grid_barrier(int* cnt, int* gen, int target) {
  __syncthreads();
  if (threadIdx.x == 0) {
    __threadfence();
    const int old = __hip_atomic_fetch_add(cnt, 1, __ATOMIC_ACQ_REL,
                                           __HIP_MEMORY_SCOPE_AGENT);
    if (old == target - 1) {
      __hip_atomic_store(gen, target, __ATOMIC_RELEASE, __HIP_MEMORY_SCOPE_AGENT);
    } else {
      while (__hip_atomic_load(gen, __ATOMIC_RELAXED, __HIP_MEMORY_SCOPE_AGENT) <
             target) {
        __builtin_amdgcn_s_sleep(2);
      }
      __builtin_amdgcn_fence(__ATOMIC_ACQUIRE, "agent");
    }
  }
  __syncthreads();
}

// ---------------------------------------------------------------------------
// K2: persistent BiLSTM with MFMA. 128 wgs x 256 thr (1/CU).
//   wg = (dir, colgroup j0 = 16 h-cols, mhalf m0 = 64 batch rows)
//   wave wv = one 16-row M-tile; 4 N-tiles = gates i,f,g,o (16 cols each).
//   W (bf16) in LDS, staged once. h double-buffered bf16 in global.
//   c state entirely in VGPRs (lane owns (b,j) pairs, static over steps).
// ---------------------------------------------------------------------------
__global__ __launch_bounds__(256, 1) void bilstm_kernel(
    const unsigned short* __restrict__ xsb,
    const float* __restrict__ Wih_f, const float* __restrict__ Whh_f,
    const float* __restrict__ bih_f, const float* __restrict__ bhh_f,
    const float* __restrict__ Wih_b, const float* __restrict__ Whh_b,
    const float* __restrict__ bih_b, const float* __restrict__ bhh_b,
    unsigned short* __restrict__ hbuf, unsigned short* __restrict__ hs,
    int* __restrict__ bar) {
  const int wg = blockIdx.x;
  const int dir = wg >> 6;
  const int sub = wg & 63;
  const int j0 = (sub & 31) * 16;  // h-column group
  const int m0 = (sub >> 5) * 64;  // batch-row half
  const int tid = threadIdx.x;
  const int wv = tid >> 6, lane = tid & 63;
  const int ln = lane & 15, kk = lane >> 4;

  const float* Wih = dir ? Wih_b : Wih_f;
  const float* Whh = dir ? Whh_b : Whh_f;
  const float* bih = dir ? bih_b : bih_f;
  const float* bhh = dir ? bhh_b : bhh_f;
  int* cnt = bar + dir * 64;
  int* gen = bar + dir * 64 + 32;

  __shared__ unsigned short Wl[64][WLD];  // 64 gate-cols x 768 k, bf16, ~99 KB

  // Stage weights f32->bf16 into LDS once. Row r = gate*16 + jj.
  for (int idx = tid; idx < 64 * 192; idx += 256) {
    const int r = idx / 192;
    const int k4 = (idx - r * 192) * 4;
    const int g = r >> 4, jj = r & 15;
    const int grow = g * HH + j0 + jj;
    float4 v;
    if (k4 < EE) v = *(const float4*)(Wih + (size_t)grow * EE + k4);
    else v = *(const float4*)(Whh + (size_t)grow * HH + (k4 - EE));
    ushort4 o;
    o.x = f2bf(v.x); o.y = f2bf(v.y); o.z = f2bf(v.z); o.w = f2bf(v.w);
    *(ushort4*)&Wl[r][k4] = o;
  }
  // zero initial h (ping buffer 0), own tile
  for (int idx = tid; idx < 64 * 16; idx += 256) {
    const int r = idx >> 4, c = idx & 15;
    hbuf[((size_t)dir * BB + m0 + r) * HH + j0 + c] = 0;
  }
  // per-lane biases (j = j0 + ln), gate order i,f,g,o
  const float bi_ = bih[0 * HH + j0 + ln] + bhh[0 * HH + j0 + ln];
  const float bf_ = bih[1 * HH + j0 + ln] + bhh[1 * HH + j0 + ln];
  const float bg_ = bih[2 * HH + j0 + ln] + bhh[2 * HH + j0 + ln];
  const float bo_ = bih[3 * HH + j0 + ln] + bhh[3 * HH + j0 + ln];

  float c[4] = {0.f, 0.f, 0.f, 0.f};

  int tgt = 1;
  grid_barrier(cnt, gen, NWGD * tgt);
  ++tgt;

  const int arow = m0 + wv * 16 + ln;  // A-fragment row for this lane
  const unsigned short* wl0 = &Wl[0 * 16 + ln][kk * 8];
  const unsigned short* wl1 = &Wl[1 * 16 + ln][kk * 8];
  const unsigned short* wl2 = &Wl[2 * 16 + ln][kk * 8];
  const unsigned short* wl3 = &Wl[3 * 16 + ln][kk * 8];

  for (int s = 0; s < TT; ++s) {
    const int t = dir ? (TT - 1 - s) : s;
    const int p = s & 1;
    const unsigned short* xr = xsb + ((size_t)t * BB + arow) * EE + kk * 8;
    const unsigned short* hr =
        hbuf + ((size_t)(p * 2 + dir) * BB + arow) * HH + kk * 8;
    f32x4 a0 = {0.f, 0.f, 0.f, 0.f}, a1 = a0, a2 = a0, a3 = a0;
#pragma unroll
    for (int kc = 0; kc < 8; ++kc) {  // x-part: k 0..255
      const bf16x8 av = *(const bf16x8*)(xr + kc * 32);
      a0 = __builtin_amdgcn_mfma_f32_16x16x32_bf16(av, *(const bf16x8*)(wl0 + kc * 32), a0, 0, 0, 0);
      a1 = __builtin_amdgcn_mfma_f32_16x16x32_bf16(av, *(const bf16x8*)(wl1 + kc * 32), a1, 0, 0, 0);
      a2 = __builtin_amdgcn_mfma_f32_16x16x32_bf16(av, *(const bf16x8*)(wl2 + kc * 32), a2, 0, 0, 0);
      a3 = __builtin_amdgcn_mfma_f32_16x16x32_bf16(av, *(const bf16x8*)(wl3 + kc * 32), a3, 0, 0, 0);
    }
#pragma unroll
    for (int kc = 0; kc < 16; ++kc) {  // h-part: k 256..767
      const bf16x8 av = *(const bf16x8*)(hr + kc * 32);
      a0 = __builtin_amdgcn_mfma_f32_16x16x32_bf16(av, *(const bf16x8*)(wl0 + EE + kc * 32), a0, 0, 0, 0);
      a1 = __builtin_amdgcn_mfma_f32_16x16x32_bf16(av, *(const bf16x8*)(wl1 + EE + kc * 32), a1, 0, 0, 0);
      a2 = __builtin_amdgcn_mfma_f32_16x16x32_bf16(av, *(const bf16x8*)(wl2 + EE + kc * 32), a2, 0, 0, 0);
      a3 = __builtin_amdgcn_mfma_f32_16x16x32_bf16(av, *(const bf16x8*)(wl3 + EE + kc * 32), a3, 0, 0, 0);
    }
    // cell update: lane holds (b = m0+wv*16+kk*4+r, j = j0+ln) for r=0..3
    unsigned short* hw = hbuf + (size_t)((p ^ 1) * 2 + dir) * BB * HH;
    unsigned short* hsw = hs + (size_t)t * BB * 1024 + (size_t)dir * HH;
#pragma unroll
    for (int r = 0; r < 4; ++r) {
      const float gi = a0[r] + bi_;
      const float gf = a1[r] + bf_;
      const float gg = a2[r] + bg_;
      const float go = a3[r] + bo_;
      const float si = 1.f / (1.f + __expf(-gi));
      const float sf = 1.f / (1.f + __expf(-gf));
      const float so = 1.f / (1.f + __expf(-go));
      const float gcl = fminf(fmaxf(gg, -30.f), 30.f);
      const float eg = __expf(-2.f * gcl);
      const float tg = (1.f - eg) / (1.f + eg);
      const float cn = fmaf(sf, c[r], si * tg);
      c[r] = cn;
      const float ccl = fminf(fmaxf(cn, -30.f), 30.f);
      const float ec = __expf(-2.f * ccl);
      const float tc = (1.f - ec) / (1.f + ec);
      const float hn = so * tc;
      const unsigned short hb = f2bf(hn);
      const int brow = m0 + wv * 16 + kk * 4 + r;
      hw[(size_t)brow * HH + j0 + ln] = hb;
      hsw[(size_t)brow * 1024 + j0 + ln] = hb;
    }
    grid_barrier(cnt, gen, NWGD * tgt);
    ++tgt;
  }
}

// ---------------------------------------------------------------------------
// K3: emissions. Wave-per-b, lanes own 16-element j-slices of the 1024-dot.
// linW read from global (28 KB, L1-resident after first b-iteration).
// ---------------------------------------------------------------------------
__global__ __launch_bounds__(256) void emissions_kernel(
    const unsigned short* __restrict__ hs, const float* __restrict__ linW,
    const float* __restrict__ linb, float* __restrict__ em) {
  const int t = blockIdx.x, tid = threadIdx.x;
  const int wv = tid >> 6, l = tid & 63;
  for (int b = wv; b < BB; b += 4) {
    const unsigned short* hr = hs + ((size_t)t * BB + b) * 1024 + l * 16;
    const u16x8 v0 = *(const u16x8*)(hr);
    const u16x8 v1 = *(const u16x8*)(hr + 8);
    float x[16];
#pragma unroll
    for (int j = 0; j < 8; ++j) {
      x[j] = bf2f(v0[j]);
      x[8 + j] = bf2f(v1[j]);
    }
    float acc[KK];
#pragma unroll
    for (int k = 0; k < KK; ++k) {
      const float* wr = linW + (size_t)k * 1024 + l * 16;
      float ssum = 0.f;
#pragma unroll
      for (int j = 0; j < 16; ++j) ssum = fmaf(x[j], wr[j], ssum);
      acc[k] = ssum;
    }
#pragma unroll
    for (int k = 0; k < KK; ++k) {
#pragma unroll
      for (int off = 32; off > 0; off >>= 1) acc[k] += __shfl_xor(acc[k], off);
    }
    if (l == 0) {
      float* o = em + ((size_t)b * TT + t) * KK;
#pragma unroll
      for (int k = 0; k < KK; ++k) o[k] = acc[k] + linb[k];
    }
  }
}

// ---------------------------------------------------------------------------
// K4: CRF forward algorithm + gold score (unchanged from round-1; passed).
// ---------------------------------------------------------------------------
__global__ __launch_bounds__(64) void crf_kernel(
    const float* __restrict__ em, const int* __restrict__ lab,
    const float* __restrict__ trans, const float* __restrict__ st_,
    const float* __restrict__ en_, float* __restrict__ partial) {
  const int b = blockIdx.x;
  const int lane = threadIdx.x;
  __shared__ float tr[49], st[7], en[7], al[2][7];
  if (lane < 49) tr[lane] = trans[lane];
  if (lane < 7) {
    st[lane] = st_[lane];
    en[lane] = en_[lane];
  }
  const float* e = em + (size_t)b * TT * KK;
  const int* lb = lab + (size_t)b * TT;
  if (lane < 7) al[0][lane] = st_[lane] + e[lane];
  __syncthreads();
  float gold = 0.f;
  int lp = lb[0];
  if (lane == 0) gold = st[lp] + e[lp];
  int p = 0;
  for (int t = 1; t < TT; ++t) {
    const float* et = e + t * KK;
    if (lane < 7) {
      float v[7], m = -1e30f;
#pragma unroll
      for (int k = 0; k < 7; ++k) {
        v[k] = al[p][k] + tr[k * 7 + lane];
        m = fmaxf(m, v[k]);
      }
      float ssum = 0.f;
#pragma unroll
      for (int k = 0; k < 7; ++k) ssum += __expf(v[k] - m);
      al[p ^ 1][lane] = m + __logf(ssum) + et[lane];
    }
    if (lane == 0) {
      const int lt = lb[t];
      gold += tr[lp * 7 + lt] + et[lt];
      lp = lt;
    }
    __syncthreads();
    p ^= 1;
  }
  if (lane == 0) {
    float m = -1e30f, v[7];
#pragma unroll
    for (int k = 0; k < 7; ++k) {
      v[k] = al[p][k] + en[k];
      m = fmaxf(m, v[k]);
    }
    float ssum = 0.f;
#pragma unroll
    for (int k = 0; k < 7; ++k) ssum += __expf(v[k] - m);
    partial[b] = (m + __logf(ssum)) - gold;
  }
}

// K5: final reduce of 128 per-sequence partials -> scalar NLL
__global__ __launch_bounds__(128) void reduce_kernel(const float* __restrict__ partial,
                                                     float* __restrict__ out) {
  __shared__ float r[128];
  const int tid = threadIdx.x;
  r[tid] = partial[tid];
  __syncthreads();
  for (int off = 64; off > 0; off >>= 1) {
    if (tid < off) r[tid] += r[tid + off];
    __syncthreads();
  }
  if (tid == 0) out[0] = r[0];
}

// ---------------------------------------------------------------------------
extern "C" void kernel_launch(void* const* d_in, const int* in_sizes, int n_in,
                              void* d_out, int out_size, void* d_ws, size_t ws_size,
                              hipStream_t stream) {
  const int* ids = (const int*)d_in[0];
  const int* lab = (const int*)d_in[1];
  const float* emb = (const float*)d_in[2];
  const float* Wih_f = (const float*)d_in[3];
  const float* Whh_f = (const float*)d_in[4];
  const float* bih_f = (const float*)d_in[5];
  const float* bhh_f = (const float*)d_in[6];
  const float* Wih_b = (const float*)d_in[7];
  const float* Whh_b = (const float*)d_in[8];
  const float* bih_b = (const float*)d_in[9];
  const float* bhh_b = (const float*)d_in[10];
  const float* linW = (const float*)d_in[11];
  const float* linb = (const float*)d_in[12];
  const float* trans = (const float*)d_in[13];
  const float* st = (const float*)d_in[14];
  const float* en = (const float*)d_in[15];
  float* out = (float*)d_out;

  // workspace layout (~85 MB)
  char* ws = (char*)d_ws;
  int* bar = (int*)ws;                                        // 512 B
  unsigned short* xsb = (unsigned short*)(ws + 512);          // T*B*E bf16 = 16.8 MB
  unsigned short* hbuf = xsb + (size_t)TT * BB * EE;          // 2*2*B*H bf16 = 0.5 MB
  unsigned short* hs = hbuf + (size_t)2 * 2 * BB * HH;        // T*B*1024 bf16 = 67 MB
  float* em = (float*)(hs + (size_t)TT * BB * 1024);          // B*T*K f32
  float* partial = em + (size_t)BB * TT * KK;

  hipMemsetAsync(bar, 0, 512, stream);

  embed_kernel<<<dim3(TT), dim3(256), 0, stream>>>(ids, emb, xsb);

  void* args[] = {(void*)&xsb,   (void*)&Wih_f, (void*)&Whh_f, (void*)&bih_f,
                  (void*)&bhh_f, (void*)&Wih_b, (void*)&Whh_b, (void*)&bih_b,
                  (void*)&bhh_b, (void*)&hbuf,  (void*)&hs,    (void*)&bar};
  hipLaunchCooperativeKernel((void*)bilstm_kernel, dim3(2 * NWGD), dim3(256),
                             args, 0, stream);

  emissions_kernel<<<dim3(TT), dim3(256), 0, stream>>>(hs, linW, linb, em);
  crf_kernel<<<dim3(BB), dim3(64), 0, stream>>>(em, lab, trans, st, en, partial);
  reduce_kernel<<<dim3(1), dim3(128), 0, stream>>>(partial, out);
}

// Round 3
// 1391.797 us; speedup vs baseline: 8.8680x; 2.8249x over previous
//
#include <hip/hip_runtime.h>
#include <hip/hip_bf16.h>

// Sizes (fixed by the problem)
#define TT 256
#define BB 128
#define EE 256
#define HH 512
#define KK 7
#define WLD 776  // padded LDS row: 768 + 8 bf16

typedef short bf16x8 __attribute__((ext_vector_type(8)));
typedef float f32x4 __attribute__((ext_vector_type(4)));
typedef unsigned short u16x8 __attribute__((ext_vector_type(8)));

__device__ __forceinline__ unsigned short f2bf(float x) {
  unsigned u = __builtin_bit_cast(unsigned, x);
  u += 0x7FFFu + ((u >> 16) & 1u);  // RNE
  return (unsigned short)(u >> 16);
}
__device__ __forceinline__ float bf2f(unsigned short b) {
  return __builtin_bit_cast(float, (unsigned)b << 16);
}

// L1-bypass 16B load (sc0): reads XCD-local L2 directly, so same-XCD
// producer stores (write-back L2) are always seen. NO waitcnt inside --
// caller batches loads then does s_waitcnt vmcnt(0) + sched_barrier(0).
__device__ __forceinline__ bf16x8 gload_sc0(const unsigned short* p) {
  bf16x8 v;
  asm volatile("global_load_dwordx4 %0, %1, off sc0"
               : "=v"(v) : "v"(p) : "memory");
  return v;
}

// ---------------------------------------------------------------------------
// K1: embedding gather -> bf16, layout xsb[t][b][e]
// ---------------------------------------------------------------------------
__global__ __launch_bounds__(256) void embed_kernel(
    const int* __restrict__ ids, const float* __restrict__ emb,
    unsigned short* __restrict__ xsb) {
  const int t = blockIdx.x, tid = threadIdx.x;
  const int b = tid >> 1, half = tid & 1;
  const int id = ids[t * BB + b];
  const float4* src = (const float4*)(emb + (size_t)id * EE + half * 128);
  unsigned short* dst = xsb + ((size_t)t * BB + b) * EE + half * 128;
#pragma unroll
  for (int i = 0; i < 32; ++i) {
    const float4 v = src[i];
    ushort4 o;
    o.x = f2bf(v.x); o.y = f2bf(v.y); o.z = f2bf(v.z); o.w = f2bf(v.w);
    *(ushort4*)(dst + i * 4) = o;
  }
}

// ---------------------------------------------------------------------------
// K2: persistent BiLSTM, XCD-local. 256 wgs x 128 thr (1 wg/CU by LDS).
//  XCD group g (from HW_REG_XCC_ID): dir = g>>2, rows = (g&3)*32.
//  wg slot s (atomic claim within XCD): h-cols [s*16, s*16+16).
//  Waves = k-split (kh): kh0 = x k-tiles 0..7 + h k-tiles 0..3,
//                        kh1 = h k-tiles 4..15.   96 MFMA each.
//  Partial gates exchanged via LDS; cell state c in VGPRs.
//  Barrier: per-XCD relaxed atomic counter (no fences, no cache nukes).
// ---------------------------------------------------------------------------
__global__ __launch_bounds__(128) void bilstm_kernel(
    const unsigned short* __restrict__ xsb,
    const float* __restrict__ Wih_f, const float* __restrict__ Whh_f,
    const float* __restrict__ bih_f, const float* __restrict__ bhh_f,
    const float* __restrict__ Wih_b, const float* __restrict__ Whh_b,
    const float* __restrict__ bih_b, const float* __restrict__ bhh_b,
    unsigned short* __restrict__ hbuf, unsigned short* __restrict__ hs,
    int* __restrict__ bar) {
  __shared__ unsigned short Wl[64][WLD];        // 99328 B
  __shared__ float gt[2][2][4][64][4];          // 16384 B  [kh][m][gate][lane][r]
  __shared__ int sinfo[2];

  const int tid = threadIdx.x;
  if (tid == 0) {
    const unsigned xcd = __builtin_amdgcn_s_getreg(14356) & 7;  // HW_REG_XCC_ID sz8
    sinfo[0] = (int)xcd;
    sinfo[1] = atomicAdd(&bar[256 + xcd * 32], 1);  // claim slot within XCD
  }
  __syncthreads();
  const int g = sinfo[0];
  const int slot = sinfo[1] & 31;
  const int dir = g >> 2;
  const int r0 = (g & 3) * 32;  // global batch-row base
  const int j0 = slot * 16;     // h-column base
  int* cnt = bar + g * 32;      // per-XCD barrier counter

  const float* Wih = dir ? Wih_b : Wih_f;
  const float* Whh = dir ? Whh_b : Whh_f;
  const float* bih = dir ? bih_b : bih_f;
  const float* bhh = dir ? bhh_b : bhh_f;

  // Stage weights f32->bf16 into LDS once. Row = gate*16 + jj, k = 0..767.
  for (int idx = tid; idx < 64 * 192; idx += 128) {
    const int r = idx / 192;
    const int k4 = (idx - r * 192) * 4;
    const int grow = (r >> 4) * HH + j0 + (r & 15);
    float4 v;
    if (k4 < EE) v = *(const float4*)(Wih + (size_t)grow * EE + k4);
    else v = *(const float4*)(Whh + (size_t)grow * HH + (k4 - EE));
    ushort4 o;
    o.x = f2bf(v.x); o.y = f2bf(v.y); o.z = f2bf(v.z); o.w = f2bf(v.w);
    *(ushort4*)&Wl[r][k4] = o;
  }
  const int lane = tid & 63, ln = lane & 15, kk = lane >> 4;
  const int kh = tid >> 6;  // wave id: k-split (also reused as m in update)

  // per-lane biases (col j0+ln), gate order i,f,g,o
  const float bi_ = bih[0 * HH + j0 + ln] + bhh[0 * HH + j0 + ln];
  const float bf_ = bih[1 * HH + j0 + ln] + bhh[1 * HH + j0 + ln];
  const float bg_ = bih[2 * HH + j0 + ln] + bhh[2 * HH + j0 + ln];
  const float bo_ = bih[3 * HH + j0 + ln] + bhh[3 * HH + j0 + ln];

  // B-fragment LDS pointers per gate (lane ln = gate-col, kk = k-subgroup)
  const unsigned short* wlp0 = &Wl[0 * 16 + ln][kk * 8];
  const unsigned short* wlp1 = &Wl[1 * 16 + ln][kk * 8];
  const unsigned short* wlp2 = &Wl[2 * 16 + ln][kk * 8];
  const unsigned short* wlp3 = &Wl[3 * 16 + ln][kk * 8];

  float c[4] = {0.f, 0.f, 0.f, 0.f};  // cell state: (m=kh, row kk*4+r, col j0+ln)
  __syncthreads();  // weights staged

  int target = 32;
  for (int s = 0; s < TT; ++s) {
    const int t = dir ? (TT - 1 - s) : s;
    const int p = s & 1;
    f32x4 a00 = {0,0,0,0}, a01 = a00, a02 = a00, a03 = a00;  // m=0, gates ifgo
    f32x4 a10 = a00, a11 = a00, a12 = a00, a13 = a00;        // m=1

    // ---- issue h loads (sc0, batched) ----
    bf16x8 hv0[12], hv1[12];
    const unsigned short* hbase =
        hbuf + ((size_t)(p * 8 + g) * 32) * HH + kk * 8;
    const unsigned short* hp0 = hbase + (size_t)ln * HH;
    const unsigned short* hp1 = hbase + (size_t)(16 + ln) * HH;
    if (s > 0) {
      if (kh == 0) {
#pragma unroll
        for (int i = 0; i < 4; ++i) {
          hv0[i] = gload_sc0(hp0 + i * 32);
          hv1[i] = gload_sc0(hp1 + i * 32);
        }
      } else {
#pragma unroll
        for (int i = 0; i < 12; ++i) {
          hv0[i] = gload_sc0(hp0 + (4 + i) * 32);
          hv1[i] = gload_sc0(hp1 + (4 + i) * 32);
        }
      }
    }
    // ---- x-part MFMAs (kh0 only; covers h-load latency) ----
    if (kh == 0) {
      const unsigned short* xr0 = xsb + ((size_t)t * BB + r0 + ln) * EE + kk * 8;
      const unsigned short* xr1 = xr0 + 16 * EE;
#pragma unroll
      for (int kt = 0; kt < 8; ++kt) {
        const bf16x8 av0 = *(const bf16x8*)(xr0 + kt * 32);
        const bf16x8 av1 = *(const bf16x8*)(xr1 + kt * 32);
        const bf16x8 b0 = *(const bf16x8*)(wlp0 + kt * 32);
        const bf16x8 b1 = *(const bf16x8*)(wlp1 + kt * 32);
        const bf16x8 b2 = *(const bf16x8*)(wlp2 + kt * 32);
        const bf16x8 b3 = *(const bf16x8*)(wlp3 + kt * 32);
        a00 = __builtin_amdgcn_mfma_f32_16x16x32_bf16(av0, b0, a00, 0, 0, 0);
        a01 = __builtin_amdgcn_mfma_f32_16x16x32_bf16(av0, b1, a01, 0, 0, 0);
        a02 = __builtin_amdgcn_mfma_f32_16x16x32_bf16(av0, b2, a02, 0, 0, 0);
        a03 = __builtin_amdgcn_mfma_f32_16x16x32_bf16(av0, b3, a03, 0, 0, 0);
        a10 = __builtin_amdgcn_mfma_f32_16x16x32_bf16(av1, b0, a10, 0, 0, 0);
        a11 = __builtin_amdgcn_mfma_f32_16x16x32_bf16(av1, b1, a11, 0, 0, 0);
        a12 = __builtin_amdgcn_mfma_f32_16x16x32_bf16(av1, b2, a12, 0, 0, 0);
        a13 = __builtin_amdgcn_mfma_f32_16x16x32_bf16(av1, b3, a13, 0, 0, 0);
      }
    }
    // ---- h-part MFMAs ----
    if (s > 0) {
      asm volatile("s_waitcnt vmcnt(0)" ::: "memory");
      __builtin_amdgcn_sched_barrier(0);
      if (kh == 0) {
#pragma unroll
        for (int i = 0; i < 4; ++i) {
          const int kt = i;
          const bf16x8 b0 = *(const bf16x8*)(wlp0 + EE + kt * 32);
          const bf16x8 b1 = *(const bf16x8*)(wlp1 + EE + kt * 32);
          const bf16x8 b2 = *(const bf16x8*)(wlp2 + EE + kt * 32);
          const bf16x8 b3 = *(const bf16x8*)(wlp3 + EE + kt * 32);
          a00 = __builtin_amdgcn_mfma_f32_16x16x32_bf16(hv0[i], b0, a00, 0, 0, 0);
          a01 = __builtin_amdgcn_mfma_f32_16x16x32_bf16(hv0[i], b1, a01, 0, 0, 0);
          a02 = __builtin_amdgcn_mfma_f32_16x16x32_bf16(hv0[i], b2, a02, 0, 0, 0);
          a03 = __builtin_amdgcn_mfma_f32_16x16x32_bf16(hv0[i], b3, a03, 0, 0, 0);
          a10 = __builtin_amdgcn_mfma_f32_16x16x32_bf16(hv1[i], b0, a10, 0, 0, 0);
          a11 = __builtin_amdgcn_mfma_f32_16x16x32_bf16(hv1[i], b1, a11, 0, 0, 0);
          a12 = __builtin_amdgcn_mfma_f32_16x16x32_bf16(hv1[i], b2, a12, 0, 0, 0);
          a13 = __builtin_amdgcn_mfma_f32_16x16x32_bf16(hv1[i], b3, a13, 0, 0, 0);
        }
      } else {
#pragma unroll
        for (int i = 0; i < 12; ++i) {
          const int kt = 4 + i;
          const bf16x8 b0 = *(const bf16x8*)(wlp0 + EE + kt * 32);
          const bf16x8 b1 = *(const bf16x8*)(wlp1 + EE + kt * 32);
          const bf16x8 b2 = *(const bf16x8*)(wlp2 + EE + kt * 32);
          const bf16x8 b3 = *(const bf16x8*)(wlp3 + EE + kt * 32);
          a00 = __builtin_amdgcn_mfma_f32_16x16x32_bf16(hv0[i], b0, a00, 0, 0, 0);
          a01 = __builtin_amdgcn_mfma_f32_16x16x32_bf16(hv0[i], b1, a01, 0, 0, 0);
          a02 = __builtin_amdgcn_mfma_f32_16x16x32_bf16(hv0[i], b2, a02, 0, 0, 0);
          a03 = __builtin_amdgcn_mfma_f32_16x16x32_bf16(hv0[i], b3, a03, 0, 0, 0);
          a10 = __builtin_amdgcn_mfma_f32_16x16x32_bf16(hv1[i], b0, a10, 0, 0, 0);
          a11 = __builtin_amdgcn_mfma_f32_16x16x32_bf16(hv1[i], b1, a11, 0, 0, 0);
          a12 = __builtin_amdgcn_mfma_f32_16x16x32_bf16(hv1[i], b2, a12, 0, 0, 0);
          a13 = __builtin_amdgcn_mfma_f32_16x16x32_bf16(hv1[i], b3, a13, 0, 0, 0);
        }
      }
    }
    // ---- exchange partials across the two k-split waves ----
    *(f32x4*)&gt[kh][0][0][lane][0] = a00;
    *(f32x4*)&gt[kh][0][1][lane][0] = a01;
    *(f32x4*)&gt[kh][0][2][lane][0] = a02;
    *(f32x4*)&gt[kh][0][3][lane][0] = a03;
    *(f32x4*)&gt[kh][1][0][lane][0] = a10;
    *(f32x4*)&gt[kh][1][1][lane][0] = a11;
    *(f32x4*)&gt[kh][1][2][lane][0] = a12;
    *(f32x4*)&gt[kh][1][3][lane][0] = a13;
    __syncthreads();
    // ---- cell update: this wave handles mtile mu = kh ----
    {
      const int mu = kh;
      unsigned short* hw =
          hbuf + ((size_t)((p ^ 1) * 8 + g) * 32 + mu * 16 + kk * 4) * HH + j0 + ln;
      unsigned short* hsw =
          hs + ((size_t)t * BB + r0 + mu * 16 + kk * 4) * 1024 + dir * HH + j0 + ln;
#pragma unroll
      for (int r = 0; r < 4; ++r) {
        const float gi = gt[0][mu][0][lane][r] + gt[1][mu][0][lane][r] + bi_;
        const float gf = gt[0][mu][1][lane][r] + gt[1][mu][1][lane][r] + bf_;
        const float gg = gt[0][mu][2][lane][r] + gt[1][mu][2][lane][r] + bg_;
        const float go = gt[0][mu][3][lane][r] + gt[1][mu][3][lane][r] + bo_;
        const float si = 1.f / (1.f + __expf(-gi));
        const float sf = 1.f / (1.f + __expf(-gf));
        const float so = 1.f / (1.f + __expf(-go));
        const float gcl = fminf(fmaxf(gg, -30.f), 30.f);
        const float eg = __expf(-2.f * gcl);
        const float tg = (1.f - eg) / (1.f + eg);
        const float cn = fmaf(sf, c[r], si * tg);
        c[r] = cn;
        const float ccl = fminf(fmaxf(cn, -30.f), 30.f);
        const float ec = __expf(-2.f * ccl);
        const float tc = (1.f - ec) / (1.f + ec);
        const float hn = so * tc;
        const unsigned short hb = f2bf(hn);
        hw[(size_t)r * HH] = hb;
        hsw[(size_t)r * 1024] = hb;
      }
    }
    // ---- XCD barrier: relaxed atomics only (no cache maintenance).
    // __syncthreads drains each wave's vmcnt before s_barrier, so all h
    // stores are committed to the XCD-local L2 before tid0 arrives.
    __syncthreads();
    if (tid == 0) {
      __hip_atomic_fetch_add(cnt, 1, __ATOMIC_RELAXED, __HIP_MEMORY_SCOPE_AGENT);
      while (__hip_atomic_load(cnt, __ATOMIC_RELAXED, __HIP_MEMORY_SCOPE_AGENT) <
             target) {
        __builtin_amdgcn_s_sleep(1);
      }
    }
    __syncthreads();
    target += 32;
  }
}

// ---------------------------------------------------------------------------
// K3: emissions. Wave-per-b, lanes own 16-element j-slices of the 1024-dot.
// ---------------------------------------------------------------------------
__global__ __launch_bounds__(256) void emissions_kernel(
    const unsigned short* __restrict__ hs, const float* __restrict__ linW,
    const float* __restrict__ linb, float* __restrict__ em) {
  const int t = blockIdx.x, tid = threadIdx.x;
  const int wv = tid >> 6, l = tid & 63;
  for (int b = wv; b < BB; b += 4) {
    const unsigned short* hr = hs + ((size_t)t * BB + b) * 1024 + l * 16;
    const u16x8 v0 = *(const u16x8*)(hr);
    const u16x8 v1 = *(const u16x8*)(hr + 8);
    float x[16];
#pragma unroll
    for (int j = 0; j < 8; ++j) {
      x[j] = bf2f(v0[j]);
      x[8 + j] = bf2f(v1[j]);
    }
    float acc[KK];
#pragma unroll
    for (int k = 0; k < KK; ++k) {
      const float* wr = linW + (size_t)k * 1024 + l * 16;
      float ssum = 0.f;
#pragma unroll
      for (int j = 0; j < 16; ++j) ssum = fmaf(x[j], wr[j], ssum);
      acc[k] = ssum;
    }
#pragma unroll
    for (int k = 0; k < KK; ++k) {
#pragma unroll
      for (int off = 32; off > 0; off >>= 1) acc[k] += __shfl_xor(acc[k], off);
    }
    if (l == 0) {
      float* o = em + ((size_t)b * TT + t) * KK;
#pragma unroll
      for (int k = 0; k < KK; ++k) o[k] = acc[k] + linb[k];
    }
  }
}

// ---------------------------------------------------------------------------
// K4: CRF forward algorithm + gold score.
// ---------------------------------------------------------------------------
__global__ __launch_bounds__(64) void crf_kernel(
    const float* __restrict__ em, const int* __restrict__ lab,
    const float* __restrict__ trans, const float* __restrict__ st_,
    const float* __restrict__ en_, float* __restrict__ partial) {
  const int b = blockIdx.x;
  const int lane = threadIdx.x;
  __shared__ float tr[49], st[7], en[7], al[2][7];
  if (lane < 49) tr[lane] = trans[lane];
  if (lane < 7) {
    st[lane] = st_[lane];
    en[lane] = en_[lane];
  }
  const float* e = em + (size_t)b * TT * KK;
  const int* lb = lab + (size_t)b * TT;
  if (lane < 7) al[0][lane] = st_[lane] + e[lane];
  __syncthreads();
  float gold = 0.f;
  int lp = lb[0];
  if (lane == 0) gold = st[lp] + e[lp];
  int p = 0;
  for (int t = 1; t < TT; ++t) {
    const float* et = e + t * KK;
    if (lane < 7) {
      float v[7], m = -1e30f;
#pragma unroll
      for (int k = 0; k < 7; ++k) {
        v[k] = al[p][k] + tr[k * 7 + lane];
        m = fmaxf(m, v[k]);
      }
      float ssum = 0.f;
#pragma unroll
      for (int k = 0; k < 7; ++k) ssum += __expf(v[k] - m);
      al[p ^ 1][lane] = m + __logf(ssum) + et[lane];
    }
    if (lane == 0) {
      const int lt = lb[t];
      gold += tr[lp * 7 + lt] + et[lt];
      lp = lt;
    }
    __syncthreads();
    p ^= 1;
  }
  if (lane == 0) {
    float m = -1e30f, v[7];
#pragma unroll
    for (int k = 0; k < 7; ++k) {
      v[k] = al[p][k] + en[k];
      m = fmaxf(m, v[k]);
    }
    float ssum = 0.f;
#pragma unroll
    for (int k = 0; k < 7; ++k) ssum += __expf(v[k] - m);
    partial[b] = (m + __logf(ssum)) - gold;
  }
}

// K5: final reduce
__global__ __launch_bounds__(128) void reduce_kernel(const float* __restrict__ partial,
                                                     float* __restrict__ out) {
  __shared__ float r[128];
  const int tid = threadIdx.x;
  r[tid] = partial[tid];
  __syncthreads();
  for (int off = 64; off > 0; off >>= 1) {
    if (tid < off) r[tid] += r[tid + off];
    __syncthreads();
  }
  if (tid == 0) out[0] = r[0];
}

// ---------------------------------------------------------------------------
extern "C" void kernel_launch(void* const* d_in, const int* in_sizes, int n_in,
                              void* d_out, int out_size, void* d_ws, size_t ws_size,
                              hipStream_t stream) {
  const int* ids = (const int*)d_in[0];
  const int* lab = (const int*)d_in[1];
  const float* emb = (const float*)d_in[2];
  const float* Wih_f = (const float*)d_in[3];
  const float* Whh_f = (const float*)d_in[4];
  const float* bih_f = (const float*)d_in[5];
  const float* bhh_f = (const float*)d_in[6];
  const float* Wih_b = (const float*)d_in[7];
  const float* Whh_b = (const float*)d_in[8];
  const float* bih_b = (const float*)d_in[9];
  const float* bhh_b = (const float*)d_in[10];
  const float* linW = (const float*)d_in[11];
  const float* linb = (const float*)d_in[12];
  const float* trans = (const float*)d_in[13];
  const float* st = (const float*)d_in[14];
  const float* en = (const float*)d_in[15];
  float* out = (float*)d_out;

  // workspace layout (~85 MB)
  char* ws = (char*)d_ws;
  int* bar = (int*)ws;                                   // 2 KB: cnt[8] + slotcnt[8]
  unsigned short* xsb = (unsigned short*)(ws + 2048);    // T*B*E bf16 = 16.8 MB
  unsigned short* hbuf = xsb + (size_t)TT * BB * EE;     // 2*8*32*512 bf16 = 0.5 MB
  unsigned short* hs = hbuf + (size_t)2 * 8 * 32 * HH;   // T*B*1024 bf16 = 67 MB
  float* em = (float*)(hs + (size_t)TT * BB * 1024);
  float* partial = em + (size_t)BB * TT * KK;

  hipMemsetAsync(bar, 0, 2048, stream);

  embed_kernel<<<dim3(TT), dim3(256), 0, stream>>>(ids, emb, xsb);

  void* args[] = {(void*)&xsb,   (void*)&Wih_f, (void*)&Whh_f, (void*)&bih_f,
                  (void*)&bhh_f, (void*)&Wih_b, (void*)&Whh_b, (void*)&bih_b,
                  (void*)&bhh_b, (void*)&hbuf,  (void*)&hs,    (void*)&bar};
  hipLaunchCooperativeKernel((void*)bilstm_kernel, dim3(256), dim3(128),
                             args, 0, stream);

  emissions_kernel<<<dim3(TT), dim3(256), 0, stream>>>(hs, linW, linb, em);
  crf_kernel<<<dim3(BB), dim3(64), 0, stream>>>(em, lab, trans, st, en, partial);
  reduce_kernel<<<dim3(1), dim3(128), 0, stream>>>(partial, out);
}